// Round 4
// baseline (162.344 us; speedup 1.0000x reference)
//
#include <hip/hip_runtime.h>

// B=4, H=W=64, D=256, N=8, K=V=32, H2=W2=32, HW=4096, M=1024 pooled/batch.

typedef _Float16 f16x8 __attribute__((ext_vector_type(8)));
typedef _Float16 f16x4 __attribute__((ext_vector_type(4)));
typedef float    f32x4 __attribute__((ext_vector_type(4)));

#define F16(x) static_cast<_Float16>(x)

#if __has_builtin(__builtin_amdgcn_exp2f)
#define EXP2(x) __builtin_amdgcn_exp2f(x)
#else
#define EXP2(x) exp2f(x)
#endif

// async global->LDS DMA, 16 B per lane; lane i lands at (uniform base) + i*16
__device__ __forceinline__ void gl_lds16(const void* g, void* l) {
    __builtin_amdgcn_global_load_lds(
        (const __attribute__((address_space(1))) unsigned int*)g,
        (__attribute__((address_space(3))) unsigned int*)l, 16, 0, 0);
}

// ---------------- prep: weights -> f16 transposed Wt[mat][o][d] -------------
// LDS 32x33 tile transpose: coalesced f32 reads along o, contiguous f16
// writes along d.
__global__ __launch_bounds__(256) void prep_kernel(
    const float* __restrict__ wq, const float* __restrict__ wk,
    const float* __restrict__ wv, _Float16* __restrict__ wt) {
    __shared__ float t[32][33];
    const int blk = blockIdx.x;              // 192 = 3 mats x 64 tiles
    const int mat = blk >> 6;
    const int tile = blk & 63;
    const int d0 = (tile >> 3) * 32, o0 = (tile & 7) * 32;
    const float* w = (mat == 0) ? wq : (mat == 1 ? wk : wv);
    const int tx = threadIdx.x & 31, ty = threadIdx.x >> 5;   // ty 0..7
#pragma unroll
    for (int i = 0; i < 4; ++i)
        t[ty + i * 8][tx] = w[(d0 + ty + i * 8) * 256 + o0 + tx];
    __syncthreads();
#pragma unroll
    for (int i = 0; i < 4; ++i)
        wt[(mat << 16) + (o0 + ty + i * 8) * 256 + d0 + tx] = (_Float16)t[tx][ty + i * 8];
}

// ---------------- proj: all three 1x1-conv GEMMs in one launch --------------
// block = 64 rows x 256 cols, 4 waves; wave = ALL 64 rows x 64 cols
// (4 mc x 4 nt).  A staged once per block in LDS (f16, double-buffered,
// depth-2 pipeline, raw lgkmcnt+barrier).  See round-3 notes.
// V output is now written FRAGMENT-ORDERED for attn (see attn header):
//   half-index = bn*131072 + (key>>4)*512 + lam*8 + (v>>4)*4 + (key&3)
//   with lam = (v&15) + ((key>>2)&3)*16.  For a proj lane this is
//   lam = lane, so the wave-store spans 1 KB (vs 8 KB-strided before).
__global__ __launch_bounds__(256) void proj_kernel(
    const float* __restrict__ blob, const _Float16* __restrict__ wt,
    const float* __restrict__ bq, const float* __restrict__ bk, const float* __restrict__ bv,
    _Float16* __restrict__ qo, _Float16* __restrict__ ko, _Float16* __restrict__ vo) {
    __shared__ __align__(16) char atile[2][4096];   // [buf][64 rows x 32 k f16]

    const int tid = threadIdx.x;
    const int lane = tid & 63, wid = tid >> 6;
    const int quad = lane >> 4, l16 = lane & 15;
    int jb = blockIdx.x;                     // 576 = 64 q + 256 k + 256 v
    int job, rowblk;
    if (jb < 64)       { job = 0; rowblk = jb; }
    else if (jb < 320) { job = 1; rowblk = jb - 64; }
    else               { job = 2; rowblk = jb - 320; }
    const int rowbase = rowblk * 64;
    const int colbase = wid * 64;
    const _Float16* wmat = wt + ((size_t)job << 16);
    const float* bias = (job == 0) ? bq : (job == 1 ? bk : bv);

    // ---- staging assignment: 256 threads x 16 B granule of the A tile ----
    const int srow = tid >> 2, sc8 = tid & 3;            // row 0..63, 8-elem col
    const int sslot = srow * 4 + ((sc8 + (srow >> 2)) & 3);
    const float* aptr;                                    // global src base
    if (job == 0) {
        const int grow = rowbase + srow;
        const int bb = grow >> 10, y = (grow >> 5) & 31, x = grow & 31;
        aptr = blob + (((bb * 64 + 2 * y) * 64) + 2 * x) * 256 + sc8 * 8;
    } else {
        aptr = blob + (size_t)(rowbase + srow) * 256 + sc8 * 8;
    }

    // per-wave weight pointers
    const _Float16* wptr[4];
#pragma unroll
    for (int nt = 0; nt < 4; ++nt)
        wptr[nt] = wmat + (size_t)(colbase + nt * 16 + l16) * 256 + quad * 8;

    // af read base (per-lane, swizzled; mc adds 1024 B)
    const int aread = l16 * 64 + ((quad + (l16 >> 2)) & 3) * 16;

    f32x4 acc[4][4];
#pragma unroll
    for (int mc = 0; mc < 4; ++mc)
#pragma unroll
        for (int nt = 0; nt < 4; ++nt) acc[mc][nt] = (f32x4){0.f, 0.f, 0.f, 0.f};

    f16x8 wf[2][4];      // weight double-buffer
    float4 ar[2][2];     // A-load double-buffer (8 f32 = one 16 B granule)

    auto A_LOAD = [&](int t, float4* dst) {
        const float* p = aptr + t * 32;
        if (job == 0) {
            float4 a0 = *(const float4*)(p);
            float4 a1 = *(const float4*)(p + 4);
            float4 b0 = *(const float4*)(p + 256);
            float4 b1 = *(const float4*)(p + 260);
            float4 c0 = *(const float4*)(p + 16384);
            float4 c1 = *(const float4*)(p + 16388);
            float4 d0 = *(const float4*)(p + 16640);
            float4 d1 = *(const float4*)(p + 16644);
            dst[0].x = fmaxf(fmaxf(a0.x, b0.x), fmaxf(c0.x, d0.x));
            dst[0].y = fmaxf(fmaxf(a0.y, b0.y), fmaxf(c0.y, d0.y));
            dst[0].z = fmaxf(fmaxf(a0.z, b0.z), fmaxf(c0.z, d0.z));
            dst[0].w = fmaxf(fmaxf(a0.w, b0.w), fmaxf(c0.w, d0.w));
            dst[1].x = fmaxf(fmaxf(a1.x, b1.x), fmaxf(c1.x, d1.x));
            dst[1].y = fmaxf(fmaxf(a1.y, b1.y), fmaxf(c1.y, d1.y));
            dst[1].z = fmaxf(fmaxf(a1.z, b1.z), fmaxf(c1.z, d1.z));
            dst[1].w = fmaxf(fmaxf(a1.w, b1.w), fmaxf(c1.w, d1.w));
        } else {
            dst[0] = *(const float4*)(p);
            dst[1] = *(const float4*)(p + 4);
        }
    };
    auto A_WRITE = [&](int buf, const float4* src) {
        auto c0 = __builtin_amdgcn_cvt_pkrtz(src[0].x, src[0].y);
        auto c1 = __builtin_amdgcn_cvt_pkrtz(src[0].z, src[0].w);
        auto c2 = __builtin_amdgcn_cvt_pkrtz(src[1].x, src[1].y);
        auto c3 = __builtin_amdgcn_cvt_pkrtz(src[1].z, src[1].w);
        f16x8 v = {F16(c0[0]), F16(c0[1]), F16(c1[0]), F16(c1[1]),
                   F16(c2[0]), F16(c2[1]), F16(c3[0]), F16(c3[1])};
        *(f16x8*)(atile[buf] + sslot * 16) = v;
    };
    auto W_LOAD = [&](int t, f16x8* dst) {
#pragma unroll
        for (int nt = 0; nt < 4; ++nt) dst[nt] = *(const f16x8*)(wptr[nt] + t * 32);
    };

    // ---- prologue ----
    W_LOAD(0, wf[0]);
    A_LOAD(0, ar[0]);
    A_WRITE(0, ar[0]);
    A_LOAD(1, ar[1]);
    asm volatile("s_waitcnt lgkmcnt(0)\n\ts_barrier" ::: "memory");

#pragma unroll
    for (int s = 0; s < 8; ++s) {
        if (s < 7) W_LOAD(s + 1, wf[(s + 1) & 1]);
        f16x8 af[4];
#pragma unroll
        for (int mc = 0; mc < 4; ++mc)
            af[mc] = *(const f16x8*)(atile[s & 1] + mc * 1024 + aread);
#pragma unroll
        for (int mc = 0; mc < 4; ++mc)
#pragma unroll
            for (int nt = 0; nt < 4; ++nt)
                acc[mc][nt] = __builtin_amdgcn_mfma_f32_16x16x32_f16(
                    af[mc], wf[s & 1][nt], acc[mc][nt], 0, 0, 0);
        if (s < 7) A_WRITE((s + 1) & 1, ar[(s + 1) & 1]);
        if (s < 6) A_LOAD(s + 2, ar[s & 1]);
        if (s < 7) asm volatile("s_waitcnt lgkmcnt(0)\n\ts_barrier" ::: "memory");
    }

    // ---- epilogue: bias / scale / swish + stores ----
#pragma unroll
    for (int nt = 0; nt < 4; ++nt) {
        const int o = colbase + nt * 16 + l16;
        const float bs = bias[o];
        const int nh = o >> 5, kk = o & 31;
#pragma unroll
        for (int mc = 0; mc < 4; ++mc) {
            if (job == 0) {
#pragma unroll
                for (int r = 0; r < 4; ++r) {
                    const int grow = rowbase + mc * 16 + quad * 4 + r;
                    // scale = (1/sqrt(32)) * log2(e): attn uses exp2
                    const float x = (acc[mc][nt][r] + bs) * 0.25503508f;
                    const int bb = grow >> 10, mm = grow & 1023;
                    qo[(((bb * 8 + nh) * 1024 + mm) << 5) + kk] = (_Float16)x;
                }
            } else if (job == 1) {
#pragma unroll
                for (int r = 0; r < 4; ++r) {
                    const int grow = rowbase + mc * 16 + quad * 4 + r;
                    const float x = acc[mc][nt][r] + bs;
                    const int bb = grow >> 12, ii = grow & 4095;
                    ko[(((bb * 8 + nh) * 4096 + ii) << 5) + kk] = (_Float16)x;
                }
            } else {
                // fragment-ordered V store: key = i0 + r, v = kk
                const int grow0 = rowbase + mc * 16 + quad * 4;
                const int bb = grow0 >> 12, i0 = grow0 & 4095;
                f16x4 pv;
#pragma unroll
                for (int r = 0; r < 4; ++r) {
                    float x = acc[mc][nt][r] + bs;
                    const float sg = 1.0f / (1.0f + __expf(-x));
                    pv[r] = (_Float16)(x * sg);
                }
                // lam = (kk&15) + ((i0>>2)&3)*16; (i0>>2)&3 == quad here
                *(f16x4*)(vo + (size_t)(bb * 8 + nh) * 131072 + (i0 >> 4) * 512
                             + ((kk & 15) + quad * 16) * 8 + (kk >> 4) * 4) = pv;
            }
        }
    }
}

// ---------------- attn: zero-barrier per-wave streams, conflict-free LDS ----
// grid 512 = 32 bn (XCD swizzle: bn%8==XCD) x 16 mt; block = 8 waves, 64 rows.
// Each wave owns a PRIVATE 512-key stream (keys [wid*512,+512)) over all 64
// q-rows: no LDS sharing between waves -> NO barriers in the main loop; each
// wave syncs only its own DMA with counted vmcnt (3-step lookahead, 4 bufs).
// LDS: 8 waves x 4 bufs x (K 1KB | V 1KB) = 64 KB.
// Both LDS reads are ds_read_b128 at lane*16 (canonical conflict-free):
//   K granule lane  = K[key0+(lane&15)][(lane>>4)*8..+7]  (16 B contiguous in
//     kb -> DMA source pre-swizzle, LDS linear)
//   V granule lane  = V^T[lane&15][keys (lane>>4)*4..+3] ++ V^T[16+(lane&15)]
//     [same keys] -- vo is written in this order by proj (vf layout), so the
//     DMA source is linear 16 B/lane and one b128 read yields va0||va1.
__global__ __launch_bounds__(512, 4) void attn_kernel(
    const _Float16* __restrict__ qb,   // [32][1024][32] (pre-scaled log2e/sqrt32)
    const _Float16* __restrict__ kb,   // [32][4096][32]
    const _Float16* __restrict__ vf,   // [32][256][512] fragment-ordered halves
    float* __restrict__ out) {         // [4][1024][256]
    __shared__ __align__(16) char pool[65536];   // 8 waves x 8 KB

    const int tid = threadIdx.x;
    const int lane = tid & 63, wid = tid >> 6;
    const int quad = lane >> 4, l16 = lane & 15;
    const int bn = blockIdx.x & 31, mt = blockIdx.x >> 5;
    const int b = bn >> 3, n = bn & 7;
    const int m0 = mt * 64;
    const int key0 = wid << 9;               // wave-private key stream

    char* const lds0 = pool + wid * 8192;

    // per-lane DMA sources (16 B each; wave-load = 1 KB)
    const _Float16* kp = kb + ((size_t)bn << 17)
                            + (size_t)(key0 + (lane & 15)) * 32 + (lane >> 4) * 8;
    const _Float16* vp = vf + ((size_t)bn << 17) + (size_t)(key0 >> 4) * 512 + lane * 8;

    // Q fragments: 4 row-groups x 16 rows (L2-hot)
    f16x8 qf[4];
#pragma unroll
    for (int rg = 0; rg < 4; ++rg)
        qf[rg] = *(const f16x8*)(qb + (((size_t)(bn << 10) + m0 + rg * 16 + l16) << 5) + quad * 8);

    // prologue: stage steps 0..2
#pragma unroll
    for (int p = 0; p < 3; ++p) {
        gl_lds16(kp, lds0 + p * 2048);        kp += 512;
        gl_lds16(vp, lds0 + p * 2048 + 1024); vp += 512;
    }

    f32x4 acc[4][2];   // [rg][vc]: out^T[v=vc*16+quad*4+r][m=rg*16+l16]
#pragma unroll
    for (int rg = 0; rg < 4; ++rg) {
        acc[rg][0] = (f32x4){0.f, 0.f, 0.f, 0.f};
        acc[rg][1] = acc[rg][0];
    }
    float ps[4] = {0.f, 0.f, 0.f, 0.f};

#pragma unroll 4
    for (int s = 0; s < 32; ++s) {           // 32 x 16 keys
        if (s < 29) {                        // stage step s+3 into buf (s+3)&3
            char* nb = lds0 + ((s + 3) & 3) * 2048;
            gl_lds16(kp, nb);        kp += 512;
            gl_lds16(vp, nb + 1024); vp += 512;
            asm volatile("s_waitcnt vmcnt(6)" ::: "memory");   // step s ready
        } else if (s == 29) {
            asm volatile("s_waitcnt vmcnt(4)" ::: "memory");
        } else if (s == 30) {
            asm volatile("s_waitcnt vmcnt(2)" ::: "memory");
        } else {
            asm volatile("s_waitcnt vmcnt(0)" ::: "memory");
        }
        const char* base = lds0 + (s & 3) * 2048;
        const f16x8 kf = *(const f16x8*)(base + lane * 16);
        const f16x8 vv = *(const f16x8*)(base + 1024 + lane * 16);
        const f16x4 va0 = {vv[0], vv[1], vv[2], vv[3]};
        const f16x4 va1 = {vv[4], vv[5], vv[6], vv[7]};
#pragma unroll
        for (int rg = 0; rg < 4; ++rg) {
            f32x4 s0 = __builtin_amdgcn_mfma_f32_16x16x32_f16(kf, qf[rg], (f32x4){0.f,0.f,0.f,0.f}, 0, 0, 0);
            const float p0 = EXP2(s0[0]), p1 = EXP2(s0[1]), p2 = EXP2(s0[2]), p3 = EXP2(s0[3]);
            ps[rg] += (p0 + p1) + (p2 + p3);
            auto e0 = __builtin_amdgcn_cvt_pkrtz(p0, p1);
            auto e1 = __builtin_amdgcn_cvt_pkrtz(p2, p3);
            const f16x4 pb = {F16(e0[0]), F16(e0[1]), F16(e1[0]), F16(e1[1])};
            acc[rg][0] = __builtin_amdgcn_mfma_f32_16x16x16f16(va0, pb, acc[rg][0], 0, 0, 0);
            acc[rg][1] = __builtin_amdgcn_mfma_f32_16x16x16f16(va1, pb, acc[rg][1], 0, 0, 0);
        }
    }

    // ---- epilogue: 8-way key-split combine in (now free) LDS ----
    asm volatile("s_waitcnt vmcnt(0)" ::: "memory");
    __syncthreads();
    float* num = (float*)pool;                 // [64][33]
    float* den = (float*)(pool + 64 * 33 * 4); // [64]
    for (int i = tid; i < 64 * 33 + 64; i += 512) ((float*)pool)[i] = 0.f;
    __syncthreads();

    // sum exp-partials over the 4 quads (score rows live in quads)
#pragma unroll
    for (int rg = 0; rg < 4; ++rg) {
        ps[rg] += __shfl_xor(ps[rg], 16);
        ps[rg] += __shfl_xor(ps[rg], 32);
    }

#pragma unroll
    for (int rg = 0; rg < 4; ++rg) {
        const int m = rg * 16 + l16;
#pragma unroll
        for (int r = 0; r < 4; ++r) {
            atomicAdd(&num[m * 33 + quad * 4 + r], acc[rg][0][r]);
            atomicAdd(&num[m * 33 + 16 + quad * 4 + r], acc[rg][1][r]);
        }
        if (quad == 0) atomicAdd(&den[m], ps[rg]);
    }
    __syncthreads();

    // store: 64 m x 32 v = 2048 f32 = 512 threads x one float4
    {
        const int mloc = tid >> 3, v4 = (tid & 7) * 4;
        const float inv = 1.0f / den[mloc];
        const float* nr = num + mloc * 33 + v4;
        float4 o = {nr[0] * inv, nr[1] * inv, nr[2] * inv, nr[3] * inv};
        *(float4*)(out + (((size_t)(b << 10) + m0 + mloc) << 8) + n * 32 + v4) = o;
    }
}

// ---------------- launch -----------------------------------------------------
extern "C" void kernel_launch(void* const* d_in, const int* in_sizes, int n_in,
                              void* d_out, int out_size, void* d_ws, size_t ws_size,
                              hipStream_t stream) {
    const float* blob = (const float*)d_in[0];
    const float* wq = (const float*)d_in[1];
    const float* bq = (const float*)d_in[2];
    const float* wk = (const float*)d_in[3];
    const float* bk = (const float*)d_in[4];
    const float* wv = (const float*)d_in[5];
    const float* bv = (const float*)d_in[6];
    float* out = (float*)d_out;

    char* ws = (char*)d_ws;
    _Float16* wt = (_Float16*)(ws);                    //   393,216 B
    _Float16* ko = (_Float16*)(ws + 393216);           // 8,388,608 B
    _Float16* vo = (_Float16*)(ws + 8781824);          // 8,388,608 B
    _Float16* qo = (_Float16*)(ws + 17170432);         // 2,097,152 B

    prep_kernel<<<192, 256, 0, stream>>>(wq, wk, wv, wt);
    proj_kernel<<<576, 256, 0, stream>>>(blob, wt, bq, bk, bv, qo, ko, vo);
    attn_kernel<<<512, 512, 0, stream>>>(qo, ko, vo, out);
}

// Round 5
// 133.849 us; speedup vs baseline: 1.2129x; 1.2129x over previous
//
#include <hip/hip_runtime.h>

// B=4, H=W=64, D=256, N=8, K=V=32, H2=W2=32, HW=4096, M=1024 pooled/batch.

typedef _Float16 f16x8 __attribute__((ext_vector_type(8)));
typedef _Float16 f16x4 __attribute__((ext_vector_type(4)));
typedef float    f32x4 __attribute__((ext_vector_type(4)));

#define F16(x) static_cast<_Float16>(x)

#if __has_builtin(__builtin_amdgcn_exp2f)
#define EXP2(x) __builtin_amdgcn_exp2f(x)
#else
#define EXP2(x) exp2f(x)
#endif

// async global->LDS DMA, 16 B per lane; lane i lands at (uniform base) + i*16
__device__ __forceinline__ void gl_lds16(const void* g, void* l) {
    __builtin_amdgcn_global_load_lds(
        (const __attribute__((address_space(1))) unsigned int*)g,
        (__attribute__((address_space(3))) unsigned int*)l, 16, 0, 0);
}

// ---------------- prep: weights -> f16 transposed Wt[mat][o][d] -------------
// LDS 32x33 tile transpose: coalesced f32 reads along o, contiguous f16
// writes along d.
__global__ __launch_bounds__(256) void prep_kernel(
    const float* __restrict__ wq, const float* __restrict__ wk,
    const float* __restrict__ wv, _Float16* __restrict__ wt) {
    __shared__ float t[32][33];
    const int blk = blockIdx.x;              // 192 = 3 mats x 64 tiles
    const int mat = blk >> 6;
    const int tile = blk & 63;
    const int d0 = (tile >> 3) * 32, o0 = (tile & 7) * 32;
    const float* w = (mat == 0) ? wq : (mat == 1 ? wk : wv);
    const int tx = threadIdx.x & 31, ty = threadIdx.x >> 5;   // ty 0..7
#pragma unroll
    for (int i = 0; i < 4; ++i)
        t[ty + i * 8][tx] = w[(d0 + ty + i * 8) * 256 + o0 + tx];
    __syncthreads();
#pragma unroll
    for (int i = 0; i < 4; ++i)
        wt[(mat << 16) + (o0 + ty + i * 8) * 256 + d0 + tx] = (_Float16)t[tx][ty + i * 8];
}

// ---------------- proj: all three 1x1-conv GEMMs in one launch --------------
// block = 64 rows x 256 cols, 4 waves; wave = ALL 64 rows x 64 cols
// (4 mc x 4 nt).  A staged once per block in LDS (f16, double-buffered,
// depth-2 pipeline, raw lgkmcnt+barrier).
// V output written FRAGMENT-ORDERED for attn (vf layout, validated round 4):
//   vf[bn][key>>4][lam*8 + (v>>4)*4 + (key&3)], lam = (v&15) + ((key>>2)&3)*16.
__global__ __launch_bounds__(256) void proj_kernel(
    const float* __restrict__ blob, const _Float16* __restrict__ wt,
    const float* __restrict__ bq, const float* __restrict__ bk, const float* __restrict__ bv,
    _Float16* __restrict__ qo, _Float16* __restrict__ ko, _Float16* __restrict__ vo) {
    __shared__ __align__(16) char atile[2][4096];   // [buf][64 rows x 32 k f16]

    const int tid = threadIdx.x;
    const int lane = tid & 63, wid = tid >> 6;
    const int quad = lane >> 4, l16 = lane & 15;
    int jb = blockIdx.x;                     // 576 = 64 q + 256 k + 256 v
    int job, rowblk;
    if (jb < 64)       { job = 0; rowblk = jb; }
    else if (jb < 320) { job = 1; rowblk = jb - 64; }
    else               { job = 2; rowblk = jb - 320; }
    const int rowbase = rowblk * 64;
    const int colbase = wid * 64;
    const _Float16* wmat = wt + ((size_t)job << 16);
    const float* bias = (job == 0) ? bq : (job == 1 ? bk : bv);

    // ---- staging assignment: 256 threads x 16 B granule of the A tile ----
    const int srow = tid >> 2, sc8 = tid & 3;            // row 0..63, 8-elem col
    const int sslot = srow * 4 + ((sc8 + (srow >> 2)) & 3);
    const float* aptr;                                    // global src base
    if (job == 0) {
        const int grow = rowbase + srow;
        const int bb = grow >> 10, y = (grow >> 5) & 31, x = grow & 31;
        aptr = blob + (((bb * 64 + 2 * y) * 64) + 2 * x) * 256 + sc8 * 8;
    } else {
        aptr = blob + (size_t)(rowbase + srow) * 256 + sc8 * 8;
    }

    // per-wave weight pointers
    const _Float16* wptr[4];
#pragma unroll
    for (int nt = 0; nt < 4; ++nt)
        wptr[nt] = wmat + (size_t)(colbase + nt * 16 + l16) * 256 + quad * 8;

    // af read base (per-lane, swizzled; mc adds 1024 B)
    const int aread = l16 * 64 + ((quad + (l16 >> 2)) & 3) * 16;

    f32x4 acc[4][4];
#pragma unroll
    for (int mc = 0; mc < 4; ++mc)
#pragma unroll
        for (int nt = 0; nt < 4; ++nt) acc[mc][nt] = (f32x4){0.f, 0.f, 0.f, 0.f};

    f16x8 wf[2][4];      // weight double-buffer
    float4 ar[2][2];     // A-load double-buffer (8 f32 = one 16 B granule)

    auto A_LOAD = [&](int t, float4* dst) {
        const float* p = aptr + t * 32;
        if (job == 0) {
            float4 a0 = *(const float4*)(p);
            float4 a1 = *(const float4*)(p + 4);
            float4 b0 = *(const float4*)(p + 256);
            float4 b1 = *(const float4*)(p + 260);
            float4 c0 = *(const float4*)(p + 16384);
            float4 c1 = *(const float4*)(p + 16388);
            float4 d0 = *(const float4*)(p + 16640);
            float4 d1 = *(const float4*)(p + 16644);
            dst[0].x = fmaxf(fmaxf(a0.x, b0.x), fmaxf(c0.x, d0.x));
            dst[0].y = fmaxf(fmaxf(a0.y, b0.y), fmaxf(c0.y, d0.y));
            dst[0].z = fmaxf(fmaxf(a0.z, b0.z), fmaxf(c0.z, d0.z));
            dst[0].w = fmaxf(fmaxf(a0.w, b0.w), fmaxf(c0.w, d0.w));
            dst[1].x = fmaxf(fmaxf(a1.x, b1.x), fmaxf(c1.x, d1.x));
            dst[1].y = fmaxf(fmaxf(a1.y, b1.y), fmaxf(c1.y, d1.y));
            dst[1].z = fmaxf(fmaxf(a1.z, b1.z), fmaxf(c1.z, d1.z));
            dst[1].w = fmaxf(fmaxf(a1.w, b1.w), fmaxf(c1.w, d1.w));
        } else {
            dst[0] = *(const float4*)(p);
            dst[1] = *(const float4*)(p + 4);
        }
    };
    auto A_WRITE = [&](int buf, const float4* src) {
        auto c0 = __builtin_amdgcn_cvt_pkrtz(src[0].x, src[0].y);
        auto c1 = __builtin_amdgcn_cvt_pkrtz(src[0].z, src[0].w);
        auto c2 = __builtin_amdgcn_cvt_pkrtz(src[1].x, src[1].y);
        auto c3 = __builtin_amdgcn_cvt_pkrtz(src[1].z, src[1].w);
        f16x8 v = {F16(c0[0]), F16(c0[1]), F16(c1[0]), F16(c1[1]),
                   F16(c2[0]), F16(c2[1]), F16(c3[0]), F16(c3[1])};
        *(f16x8*)(atile[buf] + sslot * 16) = v;
    };
    auto W_LOAD = [&](int t, f16x8* dst) {
#pragma unroll
        for (int nt = 0; nt < 4; ++nt) dst[nt] = *(const f16x8*)(wptr[nt] + t * 32);
    };

    // ---- prologue ----
    W_LOAD(0, wf[0]);
    A_LOAD(0, ar[0]);
    A_WRITE(0, ar[0]);
    A_LOAD(1, ar[1]);
    asm volatile("s_waitcnt lgkmcnt(0)\n\ts_barrier" ::: "memory");

#pragma unroll
    for (int s = 0; s < 8; ++s) {
        if (s < 7) W_LOAD(s + 1, wf[(s + 1) & 1]);
        f16x8 af[4];
#pragma unroll
        for (int mc = 0; mc < 4; ++mc)
            af[mc] = *(const f16x8*)(atile[s & 1] + mc * 1024 + aread);
#pragma unroll
        for (int mc = 0; mc < 4; ++mc)
#pragma unroll
            for (int nt = 0; nt < 4; ++nt)
                acc[mc][nt] = __builtin_amdgcn_mfma_f32_16x16x32_f16(
                    af[mc], wf[s & 1][nt], acc[mc][nt], 0, 0, 0);
        if (s < 7) A_WRITE((s + 1) & 1, ar[(s + 1) & 1]);
        if (s < 6) A_LOAD(s + 2, ar[s & 1]);
        if (s < 7) asm volatile("s_waitcnt lgkmcnt(0)\n\ts_barrier" ::: "memory");
    }

    // ---- epilogue: bias / scale / swish + stores ----
#pragma unroll
    for (int nt = 0; nt < 4; ++nt) {
        const int o = colbase + nt * 16 + l16;
        const float bs = bias[o];
        const int nh = o >> 5, kk = o & 31;
#pragma unroll
        for (int mc = 0; mc < 4; ++mc) {
            if (job == 0) {
#pragma unroll
                for (int r = 0; r < 4; ++r) {
                    const int grow = rowbase + mc * 16 + quad * 4 + r;
                    // scale = (1/sqrt(32)) * log2(e): attn uses exp2
                    const float x = (acc[mc][nt][r] + bs) * 0.25503508f;
                    const int bb = grow >> 10, mm = grow & 1023;
                    qo[(((bb * 8 + nh) * 1024 + mm) << 5) + kk] = (_Float16)x;
                }
            } else if (job == 1) {
#pragma unroll
                for (int r = 0; r < 4; ++r) {
                    const int grow = rowbase + mc * 16 + quad * 4 + r;
                    const float x = acc[mc][nt][r] + bs;
                    const int bb = grow >> 12, ii = grow & 4095;
                    ko[(((bb * 8 + nh) * 4096 + ii) << 5) + kk] = (_Float16)x;
                }
            } else {
                // fragment-ordered V store: key = i0 + r, v = kk
                const int grow0 = rowbase + mc * 16 + quad * 4;
                const int bb = grow0 >> 12, i0 = grow0 & 4095;
                f16x4 pv;
#pragma unroll
                for (int r = 0; r < 4; ++r) {
                    float x = acc[mc][nt][r] + bs;
                    const float sg = 1.0f / (1.0f + __expf(-x));
                    pv[r] = (_Float16)(x * sg);
                }
                // lam = (kk&15) + ((i0>>2)&3)*16; (i0>>2)&3 == quad here
                *(f16x4*)(vo + (size_t)(bb * 8 + nh) * 131072 + (i0 >> 4) * 512
                             + ((kk & 15) + quad * 16) * 8 + (kk >> 4) * 4) = pv;
            }
        }
    }
}

// ---------------- attn: R3 schedule + fragment-ordered conflict-free LDS ----
// grid 512 = 32 bn (XCD swizzle: bn%8==XCD) x 16 mt; block = 8 waves, 64 rows.
// wave (rg=wid&3, kc=wid>>2): q-rows [m0+rg*16,+16), keys [kc*2048,+2048).
// 2 shared K/V streams, each TRIPLE-buffered 64-key tiles (32 steps):
//   stream base kc*24576 + buf*8192: K tile 4 KB | V tile 4 KB,
//   each as 4 x 1 KB fragment-ordered subtiles (16 keys).
// Per step each wave issues 2 gl_lds16 for step s+2, computes step s, then
//   s_waitcnt vmcnt(2) + s_barrier  (raw asm: keeps s+2's loads in flight
//   across the barrier -- the counted-vmcnt pipeline that measured 48 us).
// LDS layouts are LINEAR in fragment order (round-4-validated):
//   K subtile granule lane = K[key0+(lane&15)][(lane>>4)*8..+7]
//     (DMA source pre-swizzled: (l16)*32 + quad*8 within the 1 KB key block)
//   V subtile granule lane = vf fragment order (proj writes it): one
//     ds_read_b128 at lane*16 yields va0||va1 directly.
// Both main-loop reads are ds_read_b128 at lane*16 -> zero bank conflicts,
// no rot math (was 6.3M conflict cycles in round 3).
__global__ __launch_bounds__(512, 4) void attn_kernel(
    const _Float16* __restrict__ qb,   // [32][1024][32] (pre-scaled log2e/sqrt32)
    const _Float16* __restrict__ kb,   // [32][4096][32]
    const _Float16* __restrict__ vf,   // [32][256][512] fragment-ordered halves
    float* __restrict__ out) {         // [4][1024][256]
    __shared__ __align__(16) char pool[49152];   // 2 streams x 3 bufs x 8 KB

    const int tid = threadIdx.x;
    const int lane = tid & 63, wid = tid >> 6;
    const int quad = lane >> 4, l16 = lane & 15;
    const int bn = blockIdx.x & 31, mt = blockIdx.x >> 5;
    const int b = bn >> 3, n = bn & 7;
    const int m0 = mt * 64;
    const int rg = wid & 3, kc = wid >> 2;

    // ---- per-wave DMA assignments: 2 wave-loads (1 KB each) per step ----
    // j = 0..15: stream kcj = j>>3, sub = j&7; sub<4 -> K subtile sub,
    // sub>=4 -> V subtile sub-4.  Both sources advance 2048 elems/step.
    const _Float16* gsrc[2];
    int ldsoff[2];
#pragma unroll
    for (int jj = 0; jj < 2; ++jj) {
        const int j = wid + jj * 8;              // 0..15
        const int kcj = j >> 3, sub = j & 7;
        if (sub < 4) {   // K subtile: pre-swizzled source, linear LDS
            gsrc[jj] = kb + ((size_t)bn << 17)
                     + (size_t)(kcj * 2048 + sub * 16 + (lane & 15)) * 32 + (lane >> 4) * 8;
            ldsoff[jj] = kcj * 24576 + sub * 1024;
        } else {         // V subtile: vf is already fragment-ordered -> linear
            gsrc[jj] = vf + ((size_t)bn << 17)
                     + (size_t)(kcj * 128 + (sub - 4)) * 512 + lane * 8;
            ldsoff[jj] = kcj * 24576 + 4096 + (sub - 4) * 1024;
        }
    }

    // Q fragment (16 rows, L2-hot)
    const f16x8 qf = *(const f16x8*)(qb + (((size_t)(bn << 10) + m0 + rg * 16 + l16) << 5) + quad * 8);

    // per-lane read base: both K and V reads are b128 at lane*16
    const int rbase = kc * 24576 + lane * 16;

    // prologue: DMA steps 0,1 into bufs 0,1
#pragma unroll
    for (int p = 0; p < 2; ++p)
#pragma unroll
        for (int jj = 0; jj < 2; ++jj) {
            gl_lds16(gsrc[jj], pool + ldsoff[jj] + p * 8192);
            gsrc[jj] += 2048;
        }
    asm volatile("s_waitcnt vmcnt(2)\n\ts_barrier" ::: "memory");   // step 0 ready

    f32x4 acc0 = (f32x4){0.f, 0.f, 0.f, 0.f};   // out^T[v=quad*4+r   ][m=rg*16+l16]
    f32x4 acc1 = acc0;                           // out^T[v=16+quad*4+r][m=rg*16+l16]
    float ps0 = 0.f;

    for (int s = 0; s < 32; ++s) {
        if (s < 30) {   // DMA step s+2 into buffer (s+2)%3
            const int nb = ((s + 2) % 3) * 8192;
#pragma unroll
            for (int jj = 0; jj < 2; ++jj) {
                gl_lds16(gsrc[jj], pool + ldsoff[jj] + nb);
                gsrc[jj] += 2048;
            }
        }
        const char* base = pool + rbase + (s % 3) * 8192;
#pragma unroll
        for (int tloc = 0; tloc < 4; ++tloc) {
            const f16x8 kf = *(const f16x8*)(base + tloc * 1024);
            const f16x8 vv = *(const f16x8*)(base + 4096 + tloc * 1024);
            const f16x4 va0 = {vv[0], vv[1], vv[2], vv[3]};
            const f16x4 va1 = {vv[4], vv[5], vv[6], vv[7]};

            f32x4 s0 = __builtin_amdgcn_mfma_f32_16x16x32_f16(kf, qf, (f32x4){0.f,0.f,0.f,0.f}, 0, 0, 0);
            const float p0 = EXP2(s0[0]), p1 = EXP2(s0[1]), p2 = EXP2(s0[2]), p3 = EXP2(s0[3]);
            ps0 += (p0 + p1) + (p2 + p3);
            auto e0 = __builtin_amdgcn_cvt_pkrtz(p0, p1);
            auto e1 = __builtin_amdgcn_cvt_pkrtz(p2, p3);
            const f16x4 pb = {F16(e0[0]), F16(e0[1]), F16(e1[0]), F16(e1[1])};
            acc0 = __builtin_amdgcn_mfma_f32_16x16x16f16(va0, pb, acc0, 0, 0, 0);
            acc1 = __builtin_amdgcn_mfma_f32_16x16x16f16(va1, pb, acc1, 0, 0, 0);
        }
        // wait for step s+1's loads (issued one full step ago), keep s+2's 2
        // loads in flight across the barrier
        if (s < 30)       asm volatile("s_waitcnt vmcnt(2)\n\ts_barrier" ::: "memory");
        else if (s == 30) asm volatile("s_waitcnt vmcnt(0)\n\ts_barrier" ::: "memory");
        else              asm volatile("s_barrier" ::: "memory");
    }

    // ---- epilogue: 2-way key-split combine in (now free) LDS ----
    float* num = (float*)pool;                 // [64][33]
    float* den = (float*)(pool + 64 * 33 * 4); // [64]
    for (int i = tid; i < 64 * 33 + 64; i += 512) ((float*)pool)[i] = 0.f;
    __syncthreads();

    // sum exp-partials over the 4 quads (score rows live in quads)
    ps0 += __shfl_xor(ps0, 16); ps0 += __shfl_xor(ps0, 32);

    const int m = rg * 16 + l16;
#pragma unroll
    for (int r = 0; r < 4; ++r) {
        atomicAdd(&num[m * 33 + quad * 4 + r], acc0[r]);
        atomicAdd(&num[m * 33 + 16 + quad * 4 + r], acc1[r]);
    }
    if (quad == 0) atomicAdd(&den[m], ps0);
    __syncthreads();

    // store: 64 m x 32 v = 2048 f32 = 512 threads x one float4
    {
        const int mloc = tid >> 3, v4 = (tid & 7) * 4;
        const float inv = 1.0f / den[mloc];
        const float* nr = num + mloc * 33 + v4;
        float4 o = {nr[0] * inv, nr[1] * inv, nr[2] * inv, nr[3] * inv};
        *(float4*)(out + (((size_t)(b << 10) + m0 + mloc) << 8) + n * 32 + v4) = o;
    }
}

// ---------------- launch -----------------------------------------------------
extern "C" void kernel_launch(void* const* d_in, const int* in_sizes, int n_in,
                              void* d_out, int out_size, void* d_ws, size_t ws_size,
                              hipStream_t stream) {
    const float* blob = (const float*)d_in[0];
    const float* wq = (const float*)d_in[1];
    const float* bq = (const float*)d_in[2];
    const float* wk = (const float*)d_in[3];
    const float* bk = (const float*)d_in[4];
    const float* wv = (const float*)d_in[5];
    const float* bv = (const float*)d_in[6];
    float* out = (float*)d_out;

    char* ws = (char*)d_ws;
    _Float16* wt = (_Float16*)(ws);                    //   393,216 B
    _Float16* ko = (_Float16*)(ws + 393216);           // 8,388,608 B
    _Float16* vo = (_Float16*)(ws + 8781824);          // 8,388,608 B
    _Float16* qo = (_Float16*)(ws + 17170432);         // 2,097,152 B

    prep_kernel<<<192, 256, 0, stream>>>(wq, wk, wv, wt);
    proj_kernel<<<576, 256, 0, stream>>>(blob, wt, bq, bk, bv, qo, ko, vo);
    attn_kernel<<<512, 512, 0, stream>>>(qo, ko, vo, out);
}